// Round 1
// baseline (2596.838 us; speedup 1.0000x reference)
//
#include <hip/hip_runtime.h>

// Op: out = (1/num_op) * sum_i ws[i] * SpMM(A_i, x),  A_i in COO (rows, cols, vals), D=128.
// N=50000, D=128, NUM_OP=8, E=400000  (sizes derived from in_sizes at launch).

#define D_DIM 128

__global__ __launch_bounds__(256) void spmm_scatter_kernel(
    const float* __restrict__ x,
    const float* __restrict__ edge_vals,
    const float* __restrict__ ws,
    const int*   __restrict__ edge_rows,
    const int*   __restrict__ edge_cols,
    float*       __restrict__ out,
    int E, float inv_num)
{
    const int  op    = blockIdx.y;
    const long base  = (long)op * (long)E;
    const float wscale = ws[op] * inv_num;

    const int lane            = threadIdx.x & 63;
    const int wave_in_block   = threadIdx.x >> 6;
    const int waves_per_block = blockDim.x >> 6;
    const int wave   = blockIdx.x * waves_per_block + wave_in_block;
    const int nwaves = gridDim.x * waves_per_block;

    // one wave per edge; lane owns floats [2*lane, 2*lane+1] of the D=128 row
    for (int e = wave; e < E; e += nwaves) {
        const int   row = edge_rows[base + e];
        const int   col = edge_cols[base + e];
        const float v   = edge_vals[base + e] * wscale;

        const float2 xv = *reinterpret_cast<const float2*>(
            x + (long)col * D_DIM + lane * 2);

        float* o = out + (long)row * D_DIM + lane * 2;
        atomicAdd(o,     xv.x * v);
        atomicAdd(o + 1, xv.y * v);
    }
}

extern "C" void kernel_launch(void* const* d_in, const int* in_sizes, int n_in,
                              void* d_out, int out_size, void* d_ws, size_t ws_size,
                              hipStream_t stream)
{
    const float* x         = (const float*)d_in[0];
    const float* edge_vals = (const float*)d_in[1];
    const float* ws        = (const float*)d_in[2];
    const int*   edge_rows = (const int*)d_in[3];
    const int*   edge_cols = (const int*)d_in[4];
    float*       out       = (float*)d_out;

    const int num_op = in_sizes[2];              // 8
    const int E      = in_sizes[1] / num_op;     // 400000
    const float inv_num = 1.0f / (float)num_op;  // K=1 -> num = num_op

    // Harness poisons d_out once and replays the graph: zero it every launch.
    hipMemsetAsync(d_out, 0, (size_t)out_size * sizeof(float), stream);

    // 256 blocks/op x 8 ops = 2048 blocks (4 waves each) -> ~390 edges/wave grid-stride.
    dim3 grid(256, num_op, 1);
    spmm_scatter_kernel<<<grid, 256, 0, stream>>>(
        x, edge_vals, ws, edge_rows, edge_cols, out, E, inv_num);
}

// Round 2
// 713.206 us; speedup vs baseline: 3.6411x; 3.6411x over previous
//
#include <hip/hip_runtime.h>

// Op: out = (1/num_op) * sum_i ws[i] * SpMM(A_i, x), COO -> on-device CSR -> gather.
// N=50000, D=128, NUM_OP=8, E=400000.

#define D_DIM 128
#define SCAN_BLOCK 1024

// ---------- fallback (round-0) atomic scatter kernel ----------
__global__ __launch_bounds__(256) void spmm_scatter_kernel(
    const float* __restrict__ x, const float* __restrict__ edge_vals,
    const float* __restrict__ ws, const int* __restrict__ edge_rows,
    const int* __restrict__ edge_cols, float* __restrict__ out,
    int E, float inv_num)
{
    const int  op   = blockIdx.y;
    const long base = (long)op * (long)E;
    const float wscale = ws[op] * inv_num;
    const int lane = threadIdx.x & 63;
    const int wave = blockIdx.x * (blockDim.x >> 6) + (threadIdx.x >> 6);
    const int nwaves = gridDim.x * (blockDim.x >> 6);
    for (int e = wave; e < E; e += nwaves) {
        const int row = edge_rows[base + e];
        const int col = edge_cols[base + e];
        const float v = edge_vals[base + e] * wscale;
        const float2 xv = *reinterpret_cast<const float2*>(x + (long)col * D_DIM + lane * 2);
        float* o = out + (long)row * D_DIM + lane * 2;
        atomicAdd(o, xv.x * v);
        atomicAdd(o + 1, xv.y * v);
    }
}

// ---------- CSR build ----------
__global__ __launch_bounds__(256) void histogram_kernel(
    const int* __restrict__ edge_rows, int* __restrict__ counts, int E)
{
    const long base = (long)blockIdx.y * (long)E;
    for (int e = blockIdx.x * blockDim.x + threadIdx.x; e < E; e += gridDim.x * blockDim.x)
        atomicAdd(&counts[edge_rows[base + e]], 1);
}

// single-block exclusive scan of counts[N] (stored in `cursors`) ->
// writes offsets[0..N] and re-initializes cursors[i] = exclusive prefix.
__global__ __launch_bounds__(SCAN_BLOCK) void scan_kernel(
    int* __restrict__ cursors, int* __restrict__ offsets, int N)
{
    __shared__ int sdata[SCAN_BLOCK];
    __shared__ int carry_s;
    if (threadIdx.x == 0) carry_s = 0;
    __syncthreads();
    for (int base = 0; base < N; base += SCAN_BLOCK) {
        const int i = base + (int)threadIdx.x;
        const int v = (i < N) ? cursors[i] : 0;
        sdata[threadIdx.x] = v;
        __syncthreads();
        for (int ofs = 1; ofs < SCAN_BLOCK; ofs <<= 1) {
            int t = (threadIdx.x >= (unsigned)ofs) ? sdata[threadIdx.x - ofs] : 0;
            __syncthreads();
            sdata[threadIdx.x] += t;
            __syncthreads();
        }
        const int incl  = sdata[threadIdx.x];
        const int carry = carry_s;                 // all threads read old carry
        if (i < N) {
            const int excl = carry + incl - v;
            offsets[i] = excl;
            cursors[i] = excl;
        }
        __syncthreads();                           // reads of carry_s done
        if (threadIdx.x == SCAN_BLOCK - 1) carry_s = carry + incl;
        __syncthreads();
    }
    if (threadIdx.x == 0) offsets[N] = carry_s;
}

__global__ __launch_bounds__(256) void scatter_build_kernel(
    const int* __restrict__ edge_rows, const int* __restrict__ edge_cols,
    const float* __restrict__ edge_vals, const float* __restrict__ ws,
    int* __restrict__ cursors, int2* __restrict__ records,
    int E, float inv_num)
{
    const int  op   = blockIdx.y;
    const long base = (long)op * (long)E;
    const float wscale = ws[op] * inv_num;
    for (int e = blockIdx.x * blockDim.x + threadIdx.x; e < E; e += gridDim.x * blockDim.x) {
        const int row = edge_rows[base + e];
        const int col = edge_cols[base + e];
        const float v = edge_vals[base + e] * wscale;
        const int pos = atomicAdd(&cursors[row], 1);
        records[pos] = make_int2(col, __float_as_int(v));
    }
}

// ---------- gather: one wave per output row ----------
__global__ __launch_bounds__(256) void gather_kernel(
    const float* __restrict__ x, const int* __restrict__ offsets,
    const int2* __restrict__ records, float* __restrict__ out, int N)
{
    const int lane = threadIdx.x & 63;
    const int row  = blockIdx.x * (blockDim.x >> 6) + (threadIdx.x >> 6);
    if (row >= N) return;

    const int start = offsets[row];
    const int end   = offsets[row + 1];

    float2 acc = make_float2(0.f, 0.f);
    int e = start;
    for (; e + 1 < end; e += 2) {            // 2-edge unroll for MLP
        const int2 r0 = records[e];
        const int2 r1 = records[e + 1];
        const float2 x0 = *reinterpret_cast<const float2*>(x + (long)r0.x * D_DIM + lane * 2);
        const float2 x1 = *reinterpret_cast<const float2*>(x + (long)r1.x * D_DIM + lane * 2);
        const float v0 = __int_as_float(r0.y);
        const float v1 = __int_as_float(r1.y);
        acc.x += v0 * x0.x + v1 * x1.x;
        acc.y += v0 * x0.y + v1 * x1.y;
    }
    if (e < end) {
        const int2 r0 = records[e];
        const float2 x0 = *reinterpret_cast<const float2*>(x + (long)r0.x * D_DIM + lane * 2);
        const float v0 = __int_as_float(r0.y);
        acc.x += v0 * x0.x;
        acc.y += v0 * x0.y;
    }
    *reinterpret_cast<float2*>(out + (long)row * D_DIM + lane * 2) = acc;
}

extern "C" void kernel_launch(void* const* d_in, const int* in_sizes, int n_in,
                              void* d_out, int out_size, void* d_ws, size_t ws_size,
                              hipStream_t stream)
{
    const float* x         = (const float*)d_in[0];
    const float* edge_vals = (const float*)d_in[1];
    const float* ws        = (const float*)d_in[2];
    const int*   edge_rows = (const int*)d_in[3];
    const int*   edge_cols = (const int*)d_in[4];
    float*       out       = (float*)d_out;

    const int num_op = in_sizes[2];               // 8
    const int E      = in_sizes[1] / num_op;      // 400000
    const int N      = in_sizes[0] / D_DIM;       // 50000
    const long Etot  = (long)num_op * (long)E;    // 3.2M
    const float inv_num = 1.0f / (float)num_op;

    // workspace layout
    const size_t off_offsets = 0;
    const size_t off_cursors = ((size_t)(N + 1) * 4 + 255) & ~(size_t)255;
    const size_t off_records = (off_cursors + (size_t)N * 4 + 255) & ~(size_t)255;
    const size_t need        = off_records + (size_t)Etot * 8;

    if (ws_size < need) {
        // fallback: atomic scatter
        hipMemsetAsync(d_out, 0, (size_t)out_size * sizeof(float), stream);
        dim3 grid(256, num_op, 1);
        spmm_scatter_kernel<<<grid, 256, 0, stream>>>(
            x, edge_vals, ws, edge_rows, edge_cols, out, E, inv_num);
        return;
    }

    int*  offsets = (int*)((char*)d_ws + off_offsets);
    int*  cursors = (int*)((char*)d_ws + off_cursors);
    int2* records = (int2*)((char*)d_ws + off_records);

    hipMemsetAsync(cursors, 0, (size_t)N * 4, stream);

    dim3 egrid(512, num_op, 1);
    histogram_kernel<<<egrid, 256, 0, stream>>>(edge_rows, cursors, E);
    scan_kernel<<<1, SCAN_BLOCK, 0, stream>>>(cursors, offsets, N);
    scatter_build_kernel<<<egrid, 256, 0, stream>>>(
        edge_rows, edge_cols, edge_vals, ws, cursors, records, E, inv_num);

    const int waves_per_block = 4;                       // 256 threads
    const int nblocks = (N + waves_per_block - 1) / waves_per_block;
    gather_kernel<<<nblocks, 256, 0, stream>>>(x, offsets, records, out, N);
}